// Round 1
// baseline (674.105 us; speedup 1.0000x reference)
//
#include <hip/hip_runtime.h>
#include <hip/hip_bf16.h>
#include <stdint.h>

typedef __attribute__((ext_vector_type(4))) float f32x4;
typedef __attribute__((ext_vector_type(8))) short bf16x8;
typedef __attribute__((ext_vector_type(8))) unsigned short u16x8;
typedef __attribute__((ext_vector_type(4))) unsigned short u16x4;

#define LEN_Q 2048
#define D_MODEL 256
#define LEN_IN 21760

static __device__ __forceinline__ unsigned short f2bf(float f) {
  unsigned int u = __float_as_uint(f);
  u += 0x7fffu + ((u >> 16) & 1u);
  return (unsigned short)(u >> 16);
}
static __device__ __forceinline__ float bf2f(unsigned int us) {
  return __uint_as_float(us << 16);
}

// ---------------------------------------------------------------------------
// Weight transpose + convert: WT[n][k] = bf16(W[k][n]),  W is [K][N] row-major
// ---------------------------------------------------------------------------
__global__ void tconv_k(const float* __restrict__ W, unsigned short* __restrict__ WT,
                        int K, int N, int total) {
  int i = blockIdx.x * 256 + threadIdx.x;
  if (i < total) {
    int nn = i / K, k = i - nn * K;
    WT[i] = f2bf(W[(size_t)k * N + nn]);
  }
}

__global__ void copyf_k(const float* __restrict__ a, float* __restrict__ o, int n) {
  int i = blockIdx.x * 256 + threadIdx.x;
  if (i < n) o[i] = a[i];
}

// q = bf16(src + pos), vectorized x4
__global__ void addcvt_k(const float* __restrict__ a, const float* __restrict__ b,
                         unsigned short* __restrict__ o, int n4) {
  int i = blockIdx.x * 256 + threadIdx.x;
  if (i < n4) {
    f32x4 x = ((const f32x4*)a)[i];
    f32x4 y = ((const f32x4*)b)[i];
    u16x4 r;
#pragma unroll
    for (int j = 0; j < 4; ++j) r[j] = f2bf(x[j] + y[j]);
    ((u16x4*)o)[i] = r;
  }
}

// ---------------------------------------------------------------------------
// MFMA GEMM: C[M][N] = A[M][K] @ B[K][N] + bias, B given transposed BT[N][K] bf16.
// BM=128, BN template (128 or 256), BK=32. 256 threads = 4 waves; wave w owns
// rows [w*32, w*32+32), all BN cols. 16x16x32 bf16 MFMA.
// A/B fragments use the SAME assumed (lane,j)->k bijection, so the result is
// independent of the HW's actual x32 k-ordering (it cancels in the k-sum).
// EPI: 0 = bf16 store, 1 = f32 store, 2 = relu + bf16 store.
// FUSEA: A = bf16(A1 + A2) computed on the fly (A1,A2 f32); else Abf bf16.
// ---------------------------------------------------------------------------
template <bool FUSEA, int BN, int EPI>
__global__ __launch_bounds__(256) void gemm_k(
    const float* __restrict__ A1, const float* __restrict__ A2,
    const unsigned short* __restrict__ Abf,
    const unsigned short* __restrict__ BT, const float* __restrict__ bias,
    float* __restrict__ Of, unsigned short* __restrict__ Ob,
    int M, int N, int K) {
  constexpr int NF = BN / 16;
  __shared__ unsigned short As[128][32];
  __shared__ unsigned short Bs[BN][32];
  const int tid = threadIdx.x;
  const int bm0 = blockIdx.x * 128;
  const int bn0 = blockIdx.y * BN;
  const int w = tid >> 6, lane = tid & 63;
  const int lr = lane & 15;
  const int lk = (lane >> 4) << 3;

  f32x4 acc[2][NF];
#pragma unroll
  for (int f = 0; f < 2; ++f)
#pragma unroll
    for (int g = 0; g < NF; ++g) acc[f][g] = (f32x4){0.f, 0.f, 0.f, 0.f};

  const int ar = tid >> 1;            // A stage: row 0..127
  const int ak = (tid & 1) << 4;      // 16 elems per thread
  constexpr int TPC = 256 / BN;       // threads per B column (2 or 1)
  constexpr int BKT = 32 / TPC;       // k-elems per thread (16 or 32)
  const int bcol = tid / TPC;
  const int bko = (tid % TPC) * BKT;

  for (int k0 = 0; k0 < K; k0 += 32) {
    if (FUSEA) {
      const float* pa = A1 + (size_t)(bm0 + ar) * K + k0 + ak;
      const float* pb = A2 + (size_t)(bm0 + ar) * K + k0 + ak;
#pragma unroll
      for (int h = 0; h < 2; ++h) {
        f32x4 u0 = *(const f32x4*)(pa + h * 8);
        f32x4 u1 = *(const f32x4*)(pa + h * 8 + 4);
        f32x4 v0 = *(const f32x4*)(pb + h * 8);
        f32x4 v1 = *(const f32x4*)(pb + h * 8 + 4);
        u16x8 t;
#pragma unroll
        for (int j = 0; j < 4; ++j) {
          t[j] = f2bf(u0[j] + v0[j]);
          t[4 + j] = f2bf(u1[j] + v1[j]);
        }
        *(u16x8*)&As[ar][ak + h * 8] = t;
      }
    } else {
      const unsigned short* pa = Abf + (size_t)(bm0 + ar) * K + k0 + ak;
#pragma unroll
      for (int h = 0; h < 2; ++h)
        *(u16x8*)&As[ar][ak + h * 8] = *(const u16x8*)(pa + h * 8);
    }
    {
      const unsigned short* pb = BT + (size_t)(bn0 + bcol) * K + k0 + bko;
#pragma unroll
      for (int h = 0; h < BKT / 8; ++h)
        *(u16x8*)&Bs[bcol][bko + h * 8] = *(const u16x8*)(pb + h * 8);
    }
    __syncthreads();
    bf16x8 af[2];
#pragma unroll
    for (int f = 0; f < 2; ++f)
      af[f] = *(const bf16x8*)&As[w * 32 + f * 16 + lr][lk];
#pragma unroll
    for (int g = 0; g < NF; ++g) {
      bf16x8 bv = *(const bf16x8*)&Bs[g * 16 + lr][lk];
#pragma unroll
      for (int f = 0; f < 2; ++f)
        acc[f][g] = __builtin_amdgcn_mfma_f32_16x16x32_bf16(af[f], bv, acc[f][g], 0, 0, 0);
    }
    __syncthreads();
  }
  // epilogue: C/D layout col=lane&15, row=(lane>>4)*4+reg (HW-verified)
#pragma unroll
  for (int f = 0; f < 2; ++f) {
    const int rg = bm0 + w * 32 + f * 16 + ((lane >> 4) << 2);
#pragma unroll
    for (int g = 0; g < NF; ++g) {
      const int cg = bn0 + g * 16 + lr;
      const float bv = bias[cg];
#pragma unroll
      for (int r = 0; r < 4; ++r) {
        float val = acc[f][g][r] + bv;
        if (EPI == 2) val = fmaxf(val, 0.f);
        size_t o = (size_t)(rg + r) * N + cg;
        if (EPI == 1) Of[o] = val;
        else Ob[o] = f2bf(val);
      }
    }
  }
}

// ---------------------------------------------------------------------------
// Deformable sampling. Block = one (n,q) row, 128 threads = 8 heads x 16
// channel-pairs. offattn[row][0:256]=offsets (h,l,p,2), [256:384]=attn logits
// (h, l*4+p). Softmax over 16 per head, bilinear gather from v bf16, weighted
// accumulate -> out bf16 [row][h*32+c].
// ---------------------------------------------------------------------------
__global__ __launch_bounds__(128) void msda_k(
    const float* __restrict__ offattn, const float* __restrict__ refp,
    const unsigned short* __restrict__ v, unsigned short* __restrict__ out) {
  const int row = blockIdx.x;
  const int n = row >> 11;
  const int t = threadIdx.x;
  const int h = t >> 4, c2 = t & 15;
  const float* oa = offattn + (size_t)row * 384;
  const float* at = oa + 256 + h * 16;
  float lg[16];
  float mx = -1e30f;
#pragma unroll
  for (int i = 0; i < 16; ++i) { lg[i] = at[i]; mx = fmaxf(mx, lg[i]); }
  float den = 0.f;
#pragma unroll
  for (int i = 0; i < 16; ++i) { lg[i] = __expf(lg[i] - mx); den += lg[i]; }
  const float rden = 1.f / den;

  const int HL[4] = {128, 64, 32, 16};
  const int S0[4] = {0, 16384, 20480, 21504};
  float acc0 = 0.f, acc1 = 0.f;
  const unsigned short* vb = v + (size_t)n * LEN_IN * 256 + h * 32 + (c2 << 1);
#pragma unroll
  for (int l = 0; l < 4; ++l) {
    const int W = HL[l], H = HL[l];
    const float Wf = (float)W;
    const int s0 = S0[l];
    const float rx = refp[(size_t)row * 8 + l * 2 + 0];
    const float ry = refp[(size_t)row * 8 + l * 2 + 1];
#pragma unroll
    for (int p = 0; p < 4; ++p) {
      const float ox = oa[h * 32 + l * 8 + p * 2 + 0];
      const float oy = oa[h * 32 + l * 8 + p * 2 + 1];
      float x = rx * Wf + ox - 0.5f;     // (rx + ox/W)*W - 0.5
      float y = ry * Wf + oy - 0.5f;
      float x0f = floorf(x), y0f = floorf(y);
      float wx = x - x0f, wy = y - y0f;
      int x0 = (int)x0f, y0 = (int)y0f;
      float wgt = lg[l * 4 + p] * rden;
#pragma unroll
      for (int cy = 0; cy < 2; ++cy) {
        int yi = y0 + cy;
        float wyf = cy ? wy : (1.f - wy);
        bool vy = (yi >= 0) & (yi < H);
        int yc = min(max(yi, 0), H - 1);
#pragma unroll
        for (int cx = 0; cx < 2; ++cx) {
          int xi = x0 + cx;
          float wxf = cx ? wx : (1.f - wx);
          bool vx = (xi >= 0) & (xi < W);
          int xc = min(max(xi, 0), W - 1);
          unsigned int pv = *(const unsigned int*)(vb + (size_t)(s0 + yc * W + xc) * 256);
          float wv = (vx & vy) ? (wgt * wyf * wxf) : 0.f;
          acc0 += wv * bf2f(pv & 0xffffu);
          acc1 += wv * bf2f(pv >> 16);
        }
      }
    }
  }
  unsigned int pr = ((unsigned int)f2bf(acc1) << 16) | (unsigned int)f2bf(acc0);
  *(unsigned int*)(out + (size_t)row * 256 + h * 32 + (c2 << 1)) = pr;
}

// ---------------------------------------------------------------------------
// Residual + LayerNorm over 256 cols. One block per row.
// ---------------------------------------------------------------------------
__global__ __launch_bounds__(256) void ln_k(
    const float* __restrict__ resid, const float* __restrict__ y,
    const float* __restrict__ g, const float* __restrict__ b,
    float* __restrict__ Of, unsigned short* __restrict__ Ob) {
  const int row = blockIdx.x, t = threadIdx.x;
  const size_t idx = (size_t)row * 256 + t;
  const float v = resid[idx] + y[idx];
  __shared__ float r1[256], r2[256];
  r1[t] = v;
  r2[t] = v * v;
  __syncthreads();
#pragma unroll
  for (int s = 128; s > 0; s >>= 1) {
    if (t < s) { r1[t] += r1[t + s]; r2[t] += r2[t + s]; }
    __syncthreads();
  }
  const float mu = r1[0] * (1.f / 256.f);
  const float var = r2[0] * (1.f / 256.f) - mu * mu;
  const float o = (v - mu) * rsqrtf(var + 1e-5f) * g[t] + b[t];
  Of[idx] = o;
  if (Ob) Ob[idx] = f2bf(o);
}

// ---------------------------------------------------------------------------
extern "C" void kernel_launch(void* const* d_in, const int* in_sizes, int n_in,
                              void* d_out, int out_size, void* d_ws, size_t ws_size,
                              hipStream_t stream) {
  const float* src   = (const float*)d_in[0];
  const float* pos   = (const float*)d_in[1];
  const float* mem   = (const float*)d_in[2];
  const float* posm  = (const float*)d_in[3];
  const float* refp  = (const float*)d_in[4];
  const float* W_off = (const float*)d_in[7];
  const float* b_off = (const float*)d_in[8];
  const float* W_at  = (const float*)d_in[9];
  const float* b_at  = (const float*)d_in[10];
  const float* W_val = (const float*)d_in[11];
  const float* b_val = (const float*)d_in[12];
  const float* W_out = (const float*)d_in[13];
  const float* b_out = (const float*)d_in[14];
  const float* g1    = (const float*)d_in[15];
  const float* be1   = (const float*)d_in[16];
  const float* W_ff1 = (const float*)d_in[17];
  const float* b_ff1 = (const float*)d_in[18];
  const float* W_ff2 = (const float*)d_in[19];
  const float* b_ff2 = (const float*)d_in[20];
  const float* g2    = (const float*)d_in[21];
  const float* be2   = (const float*)d_in[22];
  float* out = (float*)d_out;

  const int R = 8 * LEN_Q;          // 16384 query rows
  const int MV = 8 * LEN_IN;        // 174080 value rows

  char* ws = (char*)d_ws;
  size_t woff = 0;
  auto alloc = [&](size_t bytes) {
    char* p = ws + woff;
    woff += (bytes + 255) & ~(size_t)255;
    return p;
  };
  unsigned short* WT_val = (unsigned short*)alloc(256 * 256 * 2);
  unsigned short* WT_oa  = (unsigned short*)alloc(384 * 256 * 2);
  float* b_oa            = (float*)alloc(384 * 4);
  unsigned short* WT_out = (unsigned short*)alloc(256 * 256 * 2);
  unsigned short* WT_f1  = (unsigned short*)alloc(1024 * 256 * 2);
  unsigned short* WT_f2  = (unsigned short*)alloc(256 * 1024 * 2);
  unsigned short* qb     = (unsigned short*)alloc((size_t)R * 256 * 2);
  unsigned short* vb     = (unsigned short*)alloc((size_t)MV * 256 * 2);
  float* offattn         = (float*)alloc((size_t)R * 384 * 4);
  unsigned short* attno  = (unsigned short*)alloc((size_t)R * 256 * 2);
  float* tmp             = (float*)alloc((size_t)R * 256 * 4);
  float* xf              = (float*)alloc((size_t)R * 256 * 4);
  unsigned short* xb     = (unsigned short*)alloc((size_t)R * 256 * 2);
  unsigned short* hb     = (unsigned short*)alloc((size_t)R * 1024 * 2);

  // weights -> bf16 transposed
  tconv_k<<<256, 256, 0, stream>>>(W_val, WT_val, 256, 256, 65536);
  tconv_k<<<256, 256, 0, stream>>>(W_off, WT_oa, 256, 256, 65536);
  tconv_k<<<128, 256, 0, stream>>>(W_at, WT_oa + 256 * 256, 256, 128, 32768);
  tconv_k<<<256, 256, 0, stream>>>(W_out, WT_out, 256, 256, 65536);
  tconv_k<<<1024, 256, 0, stream>>>(W_ff1, WT_f1, 256, 1024, 262144);
  tconv_k<<<1024, 256, 0, stream>>>(W_ff2, WT_f2, 1024, 256, 262144);
  copyf_k<<<1, 256, 0, stream>>>(b_off, b_oa, 256);
  copyf_k<<<1, 128, 0, stream>>>(b_at, b_oa + 256, 128);

  // q = bf16(src + pos)
  addcvt_k<<<(R * 256 / 4 + 255) / 256, 256, 0, stream>>>(src, pos, qb, R * 256 / 4);

  // value proj: v = (mem+posm)@W_val + b_val -> bf16 [174080,256]
  gemm_k<true, 256, 0><<<dim3(MV / 128, 1), 256, 0, stream>>>(
      mem, posm, nullptr, WT_val, b_val, nullptr, vb, MV, 256, 256);
  // offsets + attn logits: [16384,384] f32
  gemm_k<false, 128, 1><<<dim3(R / 128, 3), 256, 0, stream>>>(
      nullptr, nullptr, qb, WT_oa, b_oa, offattn, nullptr, R, 384, 256);
  // deformable sampling -> attno bf16 [16384,256]
  msda_k<<<R, 128, 0, stream>>>(offattn, refp, vb, attno);
  // output proj
  gemm_k<false, 128, 1><<<dim3(R / 128, 2), 256, 0, stream>>>(
      nullptr, nullptr, attno, WT_out, b_out, tmp, nullptr, R, 256, 256);
  ln_k<<<R, 256, 0, stream>>>(src, tmp, g1, be1, xf, xb);
  // FFN
  gemm_k<false, 128, 2><<<dim3(R / 128, 8), 256, 0, stream>>>(
      nullptr, nullptr, xb, WT_f1, b_ff1, nullptr, hb, R, 1024, 256);
  gemm_k<false, 128, 1><<<dim3(R / 128, 2), 256, 0, stream>>>(
      nullptr, nullptr, hb, WT_f2, b_ff2, tmp, nullptr, R, 256, 1024);
  ln_k<<<R, 256, 0, stream>>>(xf, tmp, g2, be2, out, nullptr);
}

// Round 2
// 609.790 us; speedup vs baseline: 1.1055x; 1.1055x over previous
//
#include <hip/hip_runtime.h>
#include <hip/hip_bf16.h>
#include <stdint.h>

typedef __attribute__((ext_vector_type(4))) float f32x4;
typedef __attribute__((ext_vector_type(8))) short bf16x8;
typedef __attribute__((ext_vector_type(8))) unsigned short u16x8;
typedef __attribute__((ext_vector_type(4))) unsigned short u16x4;

#define LEN_Q 2048
#define D_MODEL 256
#define LEN_IN 21760

static __device__ __forceinline__ unsigned short f2bf(float f) {
  unsigned int u = __float_as_uint(f);
  u += 0x7fffu + ((u >> 16) & 1u);
  return (unsigned short)(u >> 16);
}
static __device__ __forceinline__ float bf2f(unsigned int us) {
  return __uint_as_float(us << 16);
}

// ---------------------------------------------------------------------------
// One fused prep kernel: all weight transposes (WT[n][k]=bf16(W[k][n])) + b_oa
// segments: Wv 65536 | Woff 65536 | Watt 32768 | Wout 65536 | Wff1 262144 |
//           Wff2 262144 | b_oa 384.  total 754048 elems.
// ---------------------------------------------------------------------------
__global__ __launch_bounds__(256) void prep_k(
    const float* __restrict__ Wv, const float* __restrict__ Wo,
    const float* __restrict__ Wa, const float* __restrict__ Wu,
    const float* __restrict__ W1, const float* __restrict__ W2,
    const float* __restrict__ boff, const float* __restrict__ batt,
    unsigned short* __restrict__ WTv, unsigned short* __restrict__ WToa,
    unsigned short* __restrict__ WTu, unsigned short* __restrict__ WT1,
    unsigned short* __restrict__ WT2, float* __restrict__ b_oa) {
  int i = blockIdx.x * 256 + threadIdx.x;
  if (i < 65536) { int n = i >> 8, k = i & 255; WTv[i] = f2bf(Wv[k * 256 + n]); return; }
  i -= 65536;
  if (i < 65536) { int n = i >> 8, k = i & 255; WToa[i] = f2bf(Wo[k * 256 + n]); return; }
  i -= 65536;
  if (i < 32768) { int n = i >> 8, k = i & 255; WToa[65536 + i] = f2bf(Wa[k * 128 + n]); return; }
  i -= 32768;
  if (i < 65536) { int n = i >> 8, k = i & 255; WTu[i] = f2bf(Wu[k * 256 + n]); return; }
  i -= 65536;
  if (i < 262144) { int n = i >> 8, k = i & 255; WT1[i] = f2bf(W1[k * 1024 + n]); return; }
  i -= 262144;
  if (i < 262144) { int n = i >> 10, k = i & 1023; WT2[i] = f2bf(W2[k * 256 + n]); return; }
  i -= 262144;
  if (i < 256) { b_oa[i] = boff[i]; return; }
  i -= 256;
  if (i < 128) { b_oa[256 + i] = batt[i]; }
}

// q = bf16(src + pos), vectorized x4
__global__ __launch_bounds__(256) void addcvt_k(const float* __restrict__ a,
                                                const float* __restrict__ b,
                                                unsigned short* __restrict__ o, int n4) {
  int i = blockIdx.x * 256 + threadIdx.x;
  if (i < n4) {
    f32x4 x = ((const f32x4*)a)[i];
    f32x4 y = ((const f32x4*)b)[i];
    u16x4 r;
#pragma unroll
    for (int j = 0; j < 4; ++j) r[j] = f2bf(x[j] + y[j]);
    ((u16x4*)o)[i] = r;
  }
}

// ---------------------------------------------------------------------------
// Pipelined MFMA GEMM. C[M][N] = A[M][K] @ B[K][N] + bias, B pre-transposed
// BT[N][K] bf16. 512 threads = 8 waves (WR x WC wave grid). BK=32, 2-phase
// double-buffered pipeline: stage chunk t+1 (global_load_lds for bf16 paths;
// reg-staged fused add+cvt for FUSEA) while MFMA-ing chunk t; one barrier/iter.
// A/B fragments use the SAME assumed (lane,j)->k bijection -> k-order cancels.
// EPI: 0 = bf16 store, 1 = f32 store, 2 = relu + bf16 store.
// ---------------------------------------------------------------------------
template <int FUSEA, int BM, int BN, int EPI>
__global__ __launch_bounds__(512) void gemm2_k(
    const float* __restrict__ A1, const float* __restrict__ A2,
    const unsigned short* __restrict__ Abf,
    const unsigned short* __restrict__ BT, const float* __restrict__ bias,
    float* __restrict__ Of, unsigned short* __restrict__ Ob,
    int M, int N, int K) {
  constexpr int WR = (BM == 128) ? 4 : 2;   // wave rows
  constexpr int WC = 8 / WR;                // wave cols
  constexpr int MR = BM / (16 * WR);        // 16-row frags per wave (=2)
  constexpr int NF = BN / (16 * WC);        // 16-col frags per wave
  constexpr int ABYTES = BM * 64;           // bytes per A chunk (BMx32 bf16)
  constexpr int BBYTES = BN * 64;
  __shared__ __align__(128) unsigned short As[2][BM][32];
  __shared__ __align__(128) unsigned short Bs[2][BN][32];

  const int tid = threadIdx.x;
  const int w = tid >> 6, lane = tid & 63;
  const int wr = w / WC, wc = w % WC;
  const int lr = lane & 15, lk = (lane >> 4) << 3;
  const int bm0 = blockIdx.x * BM, bn0 = blockIdx.y * BN;

  f32x4 acc[MR][NF];
#pragma unroll
  for (int m = 0; m < MR; ++m)
#pragma unroll
    for (int g = 0; g < NF; ++g) acc[m][g] = (f32x4){0.f, 0.f, 0.f, 0.f};

  // async tile stage: LDS linear fill, per-lane global src (row=off/64+lane/4)
  const int srow = lane >> 2;
  const int skb = (lane & 3) << 3;  // k-element offset (8 bf16 = 16B)
  auto stage = [&](unsigned short* lbase, const unsigned short* gbase, int kst, int bytes_) {
    for (int off = w * 1024; off < bytes_; off += 8192) {
      const unsigned short* src = gbase + (size_t)((off >> 6) + srow) * kst + skb;
      __builtin_amdgcn_global_load_lds(
          (const __attribute__((address_space(1))) unsigned int*)src,
          (__attribute__((address_space(3))) unsigned int*)((char*)lbase + off),
          16, 0, 0);
    }
  };

  // FUSEA reg staging: 128 rows x 32 k / 512 thr -> 8 f32 per array per thread
  const int arow = tid >> 2;
  const int ak8 = (tid & 3) << 3;
  f32x4 r10, r11, r20, r21;
  auto loadA = [&](int k0) {
    const float* p1 = A1 + (size_t)(bm0 + arow) * K + k0 + ak8;
    const float* p2 = A2 + (size_t)(bm0 + arow) * K + k0 + ak8;
    r10 = *(const f32x4*)p1;
    r11 = *(const f32x4*)(p1 + 4);
    r20 = *(const f32x4*)p2;
    r21 = *(const f32x4*)(p2 + 4);
  };
  auto writeA = [&](int p) {
    u16x8 tv;
#pragma unroll
    for (int j = 0; j < 4; ++j) {
      tv[j] = f2bf(r10[j] + r20[j]);
      tv[4 + j] = f2bf(r11[j] + r21[j]);
    }
    *(u16x8*)&As[p][arow][ak8] = tv;
  };

  const int NT = K >> 5;
  // prologue: fill buffer 0 with chunk 0
  stage(&Bs[0][0][0], BT + (size_t)bn0 * K, K, BBYTES);
  if (FUSEA) {
    loadA(0);
    writeA(0);
  } else {
    stage(&As[0][0][0], Abf + (size_t)bm0 * K, K, ABYTES);
  }
  __syncthreads();

  int p = 0;
  for (int t = 0; t < NT; ++t) {
    const int kn = (t + 1) << 5;
    if (t + 1 < NT) {  // issue next-chunk stage before compute
      stage(&Bs[p ^ 1][0][0], BT + (size_t)bn0 * K + kn, K, BBYTES);
      if (FUSEA) loadA(kn);
      else stage(&As[p ^ 1][0][0], Abf + (size_t)bm0 * K + kn, K, ABYTES);
    }
    bf16x8 af[MR];
#pragma unroll
    for (int m = 0; m < MR; ++m)
      af[m] = *(const bf16x8*)&As[p][wr * (BM / WR) + m * 16 + lr][lk];
#pragma unroll
    for (int g = 0; g < NF; ++g) {
      bf16x8 bv = *(const bf16x8*)&Bs[p][wc * (BN / WC) + g * 16 + lr][lk];
#pragma unroll
      for (int m = 0; m < MR; ++m)
        acc[m][g] = __builtin_amdgcn_mfma_f32_16x16x32_bf16(af[m], bv, acc[m][g], 0, 0, 0);
    }
    if (FUSEA && t + 1 < NT) writeA(p ^ 1);  // cvt+ds_write after MFMA (latency hidden)
    __syncthreads();
    p ^= 1;
  }

  // epilogue: C/D layout col=lane&15, row=(lane>>4)*4+reg
#pragma unroll
  for (int m = 0; m < MR; ++m) {
    const int rg = bm0 + wr * (BM / WR) + m * 16 + ((lane >> 4) << 2);
#pragma unroll
    for (int g = 0; g < NF; ++g) {
      const int cg = bn0 + wc * (BN / WC) + g * 16 + lr;
      const float bv = bias[cg];
#pragma unroll
      for (int r = 0; r < 4; ++r) {
        float val = acc[m][g][r] + bv;
        if (EPI == 2) val = fmaxf(val, 0.f);
        size_t o = (size_t)(rg + r) * N + cg;
        if (EPI == 1) Of[o] = val;
        else Ob[o] = f2bf(val);
      }
    }
  }
}

// ---------------------------------------------------------------------------
// Deformable sampling. Block = one (n,q) row, 128 threads = 8 heads x 16
// channel-pairs. offattn[row][0:256]=offsets (h,l,p,2), [256:384]=attn logits
// (h, l*4+p). Softmax over 16 per head, bilinear gather from v bf16, weighted
// accumulate -> out bf16 [row][h*32+c].
// ---------------------------------------------------------------------------
__global__ __launch_bounds__(128) void msda_k(
    const float* __restrict__ offattn, const float* __restrict__ refp,
    const unsigned short* __restrict__ v, unsigned short* __restrict__ out) {
  const int row = blockIdx.x;
  const int n = row >> 11;
  const int t = threadIdx.x;
  const int h = t >> 4, c2 = t & 15;
  const float* oa = offattn + (size_t)row * 384;
  const float* at = oa + 256 + h * 16;
  float lg[16];
  float mx = -1e30f;
#pragma unroll
  for (int i = 0; i < 16; ++i) { lg[i] = at[i]; mx = fmaxf(mx, lg[i]); }
  float den = 0.f;
#pragma unroll
  for (int i = 0; i < 16; ++i) { lg[i] = __expf(lg[i] - mx); den += lg[i]; }
  const float rden = 1.f / den;

  const int HL[4] = {128, 64, 32, 16};
  const int S0[4] = {0, 16384, 20480, 21504};
  float acc0 = 0.f, acc1 = 0.f;
  const unsigned short* vb = v + (size_t)n * LEN_IN * 256 + h * 32 + (c2 << 1);
#pragma unroll
  for (int l = 0; l < 4; ++l) {
    const int W = HL[l], H = HL[l];
    const float Wf = (float)W;
    const int s0 = S0[l];
    const float rx = refp[(size_t)row * 8 + l * 2 + 0];
    const float ry = refp[(size_t)row * 8 + l * 2 + 1];
#pragma unroll
    for (int p = 0; p < 4; ++p) {
      const float ox = oa[h * 32 + l * 8 + p * 2 + 0];
      const float oy = oa[h * 32 + l * 8 + p * 2 + 1];
      float x = rx * Wf + ox - 0.5f;
      float y = ry * Wf + oy - 0.5f;
      float x0f = floorf(x), y0f = floorf(y);
      float wx = x - x0f, wy = y - y0f;
      int x0 = (int)x0f, y0 = (int)y0f;
      float wgt = lg[l * 4 + p] * rden;
#pragma unroll
      for (int cy = 0; cy < 2; ++cy) {
        int yi = y0 + cy;
        float wyf = cy ? wy : (1.f - wy);
        bool vy = (yi >= 0) & (yi < H);
        int yc = min(max(yi, 0), H - 1);
#pragma unroll
        for (int cx = 0; cx < 2; ++cx) {
          int xi = x0 + cx;
          float wxf = cx ? wx : (1.f - wx);
          bool vx = (xi >= 0) & (xi < W);
          int xc = min(max(xi, 0), W - 1);
          unsigned int pv = *(const unsigned int*)(vb + (size_t)(s0 + yc * W + xc) * 256);
          float wv = (vx & vy) ? (wgt * wyf * wxf) : 0.f;
          acc0 += wv * bf2f(pv & 0xffffu);
          acc1 += wv * bf2f(pv >> 16);
        }
      }
    }
  }
  unsigned int pr = ((unsigned int)f2bf(acc1) << 16) | (unsigned int)f2bf(acc0);
  *(unsigned int*)(out + (size_t)row * 256 + h * 32 + (c2 << 1)) = pr;
}

// ---------------------------------------------------------------------------
// Residual + LayerNorm over 256 cols. One block per row, shuffle reduce.
// ---------------------------------------------------------------------------
__global__ __launch_bounds__(256) void ln_k(
    const float* __restrict__ resid, const float* __restrict__ y,
    const float* __restrict__ g, const float* __restrict__ b,
    float* __restrict__ Of, unsigned short* __restrict__ Ob) {
  const int row = blockIdx.x, t = threadIdx.x;
  const size_t idx = (size_t)row * 256 + t;
  const float v = resid[idx] + y[idx];
  float s1 = v, s2 = v * v;
#pragma unroll
  for (int d = 32; d > 0; d >>= 1) {
    s1 += __shfl_xor(s1, d, 64);
    s2 += __shfl_xor(s2, d, 64);
  }
  __shared__ float p1[4], p2[4];
  const int w = t >> 6;
  if ((t & 63) == 0) { p1[w] = s1; p2[w] = s2; }
  __syncthreads();
  const float mu = (p1[0] + p1[1] + p1[2] + p1[3]) * (1.f / 256.f);
  const float m2 = (p2[0] + p2[1] + p2[2] + p2[3]) * (1.f / 256.f);
  const float var = m2 - mu * mu;
  const float o = (v - mu) * rsqrtf(var + 1e-5f) * g[t] + b[t];
  Of[idx] = o;
  if (Ob) Ob[idx] = f2bf(o);
}

// ---------------------------------------------------------------------------
extern "C" void kernel_launch(void* const* d_in, const int* in_sizes, int n_in,
                              void* d_out, int out_size, void* d_ws, size_t ws_size,
                              hipStream_t stream) {
  const float* src   = (const float*)d_in[0];
  const float* pos   = (const float*)d_in[1];
  const float* mem   = (const float*)d_in[2];
  const float* posm  = (const float*)d_in[3];
  const float* refp  = (const float*)d_in[4];
  const float* W_off = (const float*)d_in[7];
  const float* b_off = (const float*)d_in[8];
  const float* W_at  = (const float*)d_in[9];
  const float* b_at  = (const float*)d_in[10];
  const float* W_val = (const float*)d_in[11];
  const float* b_val = (const float*)d_in[12];
  const float* W_out = (const float*)d_in[13];
  const float* b_out = (const float*)d_in[14];
  const float* g1    = (const float*)d_in[15];
  const float* be1   = (const float*)d_in[16];
  const float* W_ff1 = (const float*)d_in[17];
  const float* b_ff1 = (const float*)d_in[18];
  const float* W_ff2 = (const float*)d_in[19];
  const float* b_ff2 = (const float*)d_in[20];
  const float* g2    = (const float*)d_in[21];
  const float* be2   = (const float*)d_in[22];
  float* out = (float*)d_out;

  const int R = 8 * LEN_Q;          // 16384 query rows
  const int MV = 8 * LEN_IN;        // 174080 value rows

  char* ws = (char*)d_ws;
  size_t woff = 0;
  auto alloc = [&](size_t bytes) {
    char* p = ws + woff;
    woff += (bytes + 255) & ~(size_t)255;
    return p;
  };
  unsigned short* WT_val = (unsigned short*)alloc(256 * 256 * 2);
  unsigned short* WT_oa  = (unsigned short*)alloc(384 * 256 * 2);
  float* b_oa            = (float*)alloc(384 * 4);
  unsigned short* WT_out = (unsigned short*)alloc(256 * 256 * 2);
  unsigned short* WT_f1  = (unsigned short*)alloc(1024 * 256 * 2);
  unsigned short* WT_f2  = (unsigned short*)alloc(256 * 1024 * 2);
  unsigned short* qb     = (unsigned short*)alloc((size_t)R * 256 * 2);
  unsigned short* vb     = (unsigned short*)alloc((size_t)MV * 256 * 2);
  float* offattn         = (float*)alloc((size_t)R * 384 * 4);
  unsigned short* attno  = (unsigned short*)alloc((size_t)R * 256 * 2);
  float* tmp             = (float*)alloc((size_t)R * 256 * 4);
  float* xf              = (float*)alloc((size_t)R * 256 * 4);
  unsigned short* xb     = (unsigned short*)alloc((size_t)R * 256 * 2);
  unsigned short* hb     = (unsigned short*)alloc((size_t)R * 1024 * 2);

  // fused weight prep (754048 work items)
  prep_k<<<2946, 256, 0, stream>>>(W_val, W_off, W_at, W_out, W_ff1, W_ff2,
                                   b_off, b_at, WT_val, WT_oa, WT_out, WT_f1,
                                   WT_f2, b_oa);
  // q = bf16(src + pos)
  addcvt_k<<<4096, 256, 0, stream>>>(src, pos, qb, R * 64);

  // value proj: v = (mem+posm)@W_val + b_val -> bf16 [174080,256]
  gemm2_k<1, 128, 256, 0><<<dim3(MV / 128, 1), 512, 0, stream>>>(
      mem, posm, nullptr, WT_val, b_val, nullptr, vb, MV, 256, 256);
  // offsets + attn logits: [16384,384] f32
  gemm2_k<0, 64, 128, 1><<<dim3(R / 64, 3), 512, 0, stream>>>(
      nullptr, nullptr, qb, WT_oa, b_oa, offattn, nullptr, R, 384, 256);
  // deformable sampling -> attno bf16 [16384,256]
  msda_k<<<R, 128, 0, stream>>>(offattn, refp, vb, attno);
  // output proj
  gemm2_k<0, 64, 256, 1><<<dim3(R / 64, 1), 512, 0, stream>>>(
      nullptr, nullptr, attno, WT_out, b_out, tmp, nullptr, R, 256, 256);
  ln_k<<<R, 256, 0, stream>>>(src, tmp, g1, be1, xf, xb);
  // FFN
  gemm2_k<0, 128, 256, 2><<<dim3(R / 128, 4), 512, 0, stream>>>(
      nullptr, nullptr, xb, WT_f1, b_ff1, nullptr, hb, R, 1024, 256);
  gemm2_k<0, 64, 256, 1><<<dim3(R / 64, 1), 512, 0, stream>>>(
      nullptr, nullptr, hb, WT_f2, b_ff2, tmp, nullptr, R, 256, 1024);
  ln_k<<<R, 256, 0, stream>>>(xf, tmp, g2, be2, out, nullptr);
}